// Round 13
// baseline (324.752 us; speedup 1.0000x reference)
//
#include <hip/hip_runtime.h>
#include <math.h>

#define T_TOK 16384
#define DIM   2048
#define NE    64
#define NACT  8
#define ALPHA 1e-4f
#define EPSV  1e-9f
#define TAU   2.5e-4f

#define WPITCH 520   // shorts per W row in LDS (R7-verified layout)

typedef __attribute__((ext_vector_type(8))) short bf16x8;
typedef __attribute__((ext_vector_type(4))) float f32x4;

// RNE float->bf16 (values finite/small; no nan handling needed)
__device__ inline unsigned short bf16_rne(float f) {
    unsigned b = __float_as_uint(f);
    unsigned r = b + 0x7FFFu + ((b >> 16) & 1u);
    return (unsigned short)(r >> 16);
}

// ---------------------------------------------------------------------------
// GEMM (R11 = R7's HW-verified structure, epilogue de-atomicized):
// W k-slice (64e x 512k, bf16 hi+lo) staged+converted into LDS once per
// block (130 KB); barrier-free K-loop: x via 2 direct 64B-segment gathers
// per group (R7 k-permutation), W via ds_read_b128. Scattered-global-load
// count = 131k (the ~100cyc/load law: R10's 655k = 109us measured; R7's
// 131k structure was fast). Grid 256 = 64 token-groups x 4 k-quarters;
// block 1024 thr (16 waves), wave = 16 tok x 64 exp x 512 k.
// Epilogue: PLAIN STORES of partials to Apart[kq] (no atomics, no zeroed
// accumulator). Block 0 also zeroes the 130 scalars (replaces zero_k).
// MFMA 16x16x32 bf16, layouts m89/m120-verified.
// ---------------------------------------------------------------------------
__global__ __launch_bounds__(1024) void gemm_k(
        const float* __restrict__ x,
        const float* __restrict__ W,
        float* __restrict__ Apart,
        float* __restrict__ gz) {
    __shared__ __align__(16) unsigned short Whs[NE * WPITCH];
    __shared__ __align__(16) unsigned short Wls[NE * WPITCH];

    const int tid = threadIdx.x;
    const int kq  = blockIdx.x & 3;
    const int tg  = blockIdx.x >> 2;
    const int tokBase = tg * 256;
    const int kb  = kq * 512;

    if (blockIdx.x == 0 && tid < 130) gz[tid] = 0.0f;

    // ---- stage + convert W slice: thread (e=tid>>4, c=tid&15) does 32 k ----
    // permuted store: group-local float4 m -> shorts at (m&3)*8 + (m>>2)*4
    {
        const int e = tid >> 4;
        const int c = tid & 15;
        const float* wr = W + (size_t)e * DIM + kb + c * 32;
        unsigned short* dh = &Whs[e * WPITCH + c * 32];
        unsigned short* dl = &Wls[e * WPITCH + c * 32];
#pragma unroll
        for (int m = 0; m < 8; ++m) {
            const float4 v = *(const float4*)(wr + m * 4);
            const float f[4] = {v.x, v.y, v.z, v.w};
            unsigned short hp[4], lp[4];
#pragma unroll
            for (int u = 0; u < 4; ++u) {
                const unsigned bb = __float_as_uint(f[u]);
                const unsigned hb = bb & 0xFFFF0000u;
                hp[u] = (unsigned short)(hb >> 16);
                lp[u] = bf16_rne(f[u] - __uint_as_float(hb));
            }
            const int dpos = (m & 3) * 8 + (m >> 2) * 4;
            *(ushort4*)(dh + dpos) = *(const ushort4*)hp;
            *(ushort4*)(dl + dpos) = *(const ushort4*)lp;
        }
    }
    __syncthreads();

    const int wv   = tid >> 6;
    const int lane = tid & 63;
    const int c15  = lane & 15;
    const int q    = lane >> 4;

    // lane's k-base within a 32-group is q*4 (permuted layout)
    const float* xp = x + (size_t)(tokBase + wv * 16 + c15) * DIM + kb + q * 4;
    const unsigned short* whB = &Whs[c15 * WPITCH + q * 8];
    const unsigned short* wlB = &Wls[c15 * WPITCH + q * 8];

    f32x4 acc[4];
#pragma unroll
    for (int j = 0; j < 4; ++j) acc[j] = (f32x4){0.f, 0.f, 0.f, 0.f};

    float4 ra[2][2];
    bf16x8 rh[2][4], rl[2][4];

#define LOADSTEP(s, st) {                                                 \
        const float* xpc = xp + 32 * (st);                                \
        ra[s][0] = *(const float4*)xpc;                                   \
        ra[s][1] = *(const float4*)(xpc + 16);                            \
        _Pragma("unroll")                                                 \
        for (int j = 0; j < 4; ++j) {                                     \
            rh[s][j] = *(const bf16x8*)(whB + j * 16 * WPITCH + (st) * 32); \
            rl[s][j] = *(const bf16x8*)(wlB + j * 16 * WPITCH + (st) * 32); \
        }                                                                 \
    }

#define COMPSTEP(s) {                                                     \
        bf16x8 ah, al;                                                    \
        {                                                                 \
            float f[8] = {ra[s][0].x, ra[s][0].y, ra[s][0].z, ra[s][0].w, \
                          ra[s][1].x, ra[s][1].y, ra[s][1].z, ra[s][1].w};\
            _Pragma("unroll")                                             \
            for (int i = 0; i < 8; ++i) {                                 \
                const unsigned bb = __float_as_uint(f[i]);                \
                const unsigned hb = bb & 0xFFFF0000u;                     \
                ah[i] = (short)(hb >> 16);                                \
                al[i] = (short)bf16_rne(f[i] - __uint_as_float(hb));      \
            }                                                             \
        }                                                                 \
        _Pragma("unroll")                                                 \
        for (int j = 0; j < 4; ++j) {                                     \
            acc[j] = __builtin_amdgcn_mfma_f32_16x16x32_bf16(ah, rh[s][j], acc[j], 0, 0, 0); \
            acc[j] = __builtin_amdgcn_mfma_f32_16x16x32_bf16(ah, rl[s][j], acc[j], 0, 0, 0); \
            acc[j] = __builtin_amdgcn_mfma_f32_16x16x32_bf16(al, rh[s][j], acc[j], 0, 0, 0); \
        }                                                                 \
    }

    LOADSTEP(0, 0);
    LOADSTEP(1, 1);
#pragma unroll
    for (int c = 0; c < 16; c += 2) {
        COMPSTEP(0);
        if (c + 2 < 16) LOADSTEP(0, c + 2);
        COMPSTEP(1);
        if (c + 3 < 16) LOADSTEP(1, c + 3);
    }
#undef LOADSTEP
#undef COMPSTEP

    // ---- epilogue: plain partial stores (C: row=q*4+r token, col=16j+c15)
    float* ap = Apart + (size_t)kq * T_TOK * NE;
    const int trow = tokBase + wv * 16 + q * 4;
#pragma unroll
    for (int j = 0; j < 4; ++j)
#pragma unroll
        for (int r = 0; r < 4; ++r)
            ap[(size_t)(trow + r) * NE + 16 * j + c15] = acc[j][r];
}

// ---------------------------------------------------------------------------
// Gate (R7-verified logic): sum the 4 k-quarter partials (fixed order ->
// deterministic), store summed logits to Aout (bit-exact source for fix_k),
// sigmoid -> rank-based top-8 -> gate normalization, near-tie marking, loss
// partials. Grid 1024 x 256 (16 tok/block, 4/wave).
// ---------------------------------------------------------------------------
__global__ __launch_bounds__(256) void gate_k(
        const float* __restrict__ Apart,
        const float* __restrict__ bias,
        float* __restrict__ Aout,
        float* __restrict__ gates,
        float* __restrict__ idxf,
        float* __restrict__ gP,
        float* __restrict__ gC,
        int*   __restrict__ cntp,
        int*   __restrict__ list) {
    __shared__ __align__(16) float aff[16 * 68];
    __shared__ __align__(16) float sS[4][64];   // scores by lane
    __shared__ __align__(16) float bS[4][64];   // scores by rank
    __shared__ __align__(16) float bA[4][64];   // affinity by rank
    __shared__ float Pl[NE];
    __shared__ float Cl[NE];

    const int tid  = threadIdx.x;
    const int wv   = tid >> 6;
    const int lane = tid & 63;
    const int tokBase = blockIdx.x * 16;

    if (tid < NE) { Pl[tid] = 0.0f; Cl[tid] = 0.0f; }

    {
        const int t  = tid >> 4;
        const int e0 = (tid & 15) * 4;
        const size_t off = (size_t)(tokBase + t) * NE + e0;
        const float4 l0 = *(const float4*)(Apart + 0 * (size_t)T_TOK * NE + off);
        const float4 l1 = *(const float4*)(Apart + 1 * (size_t)T_TOK * NE + off);
        const float4 l2 = *(const float4*)(Apart + 2 * (size_t)T_TOK * NE + off);
        const float4 l3 = *(const float4*)(Apart + 3 * (size_t)T_TOK * NE + off);
        float4 lg;
        lg.x = ((l0.x + l1.x) + l2.x) + l3.x;
        lg.y = ((l0.y + l1.y) + l2.y) + l3.y;
        lg.z = ((l0.z + l1.z) + l2.z) + l3.z;
        lg.w = ((l0.w + l1.w) + l2.w) + l3.w;
        *(float4*)(Aout + off) = lg;            // logits for fix_k (bit-exact)
        float4 af;
        af.x = 1.0f / (1.0f + expf(-lg.x));
        af.y = 1.0f / (1.0f + expf(-lg.y));
        af.z = 1.0f / (1.0f + expf(-lg.z));
        af.w = 1.0f / (1.0f + expf(-lg.w));
        *(float4*)&aff[t * 68 + e0] = af;
    }
    __syncthreads();

    const float b = bias[lane];
    float pacc = 0.0f;
    float cacc = 0.0f;

    for (int it = 0; it < 4; ++it) {
        const int tl = wv * 4 + it;
        const int gt = tokBase + tl;
        const float a = aff[tl * 68 + lane];

        float rs = a;
#pragma unroll
        for (int off = 32; off; off >>= 1) rs += __shfl_xor(rs, off, 64);
        pacc += a / (rs + EPSV);

        const float s = a + b;
        sS[wv][lane] = s;
        __syncthreads();

        int rank = 0;
#pragma unroll
        for (int j4 = 0; j4 < 16; ++j4) {
            const float4 sv = *(const float4*)&sS[wv][j4 * 4];
            rank += (sv.x > s || (sv.x == s && (j4 * 4 + 0) < lane));
            rank += (sv.y > s || (sv.y == s && (j4 * 4 + 1) < lane));
            rank += (sv.z > s || (sv.z == s && (j4 * 4 + 2) < lane));
            rank += (sv.w > s || (sv.w == s && (j4 * 4 + 3) < lane));
        }
        bS[wv][rank] = s;
        bA[wv][rank] = a;
        __syncthreads();

        // marking: min adjacent gap among sorted ranks 0..8
        const float4 p0 = *(const float4*)&bS[wv][0];
        const float4 p1 = *(const float4*)&bS[wv][4];
        const float v8v = bS[wv][8];
        float gmin = p0.x - p0.y;
        gmin = fminf(gmin, p0.y - p0.z);
        gmin = fminf(gmin, p0.z - p0.w);
        gmin = fminf(gmin, p0.w - p1.x);
        gmin = fminf(gmin, p1.x - p1.y);
        gmin = fminf(gmin, p1.y - p1.z);
        gmin = fminf(gmin, p1.z - p1.w);
        gmin = fminf(gmin, p1.w - v8v);
        const bool marked = (gmin < TAU);

        const float4 a0 = *(const float4*)&bA[wv][0];
        const float4 a1 = *(const float4*)&bA[wv][4];
        const float gsum = ((((((a0.x + a0.y) + a0.z) + a0.w) + a1.x) + a1.y) + a1.z) + a1.w;
        const float inv = 1.0f / (gsum + EPSV);

        if (rank < NACT) {
            gates[(size_t)gt * NACT + rank] = a * inv;
            idxf [(size_t)gt * NACT + rank] = (float)lane;
            if (!marked) cacc += 1.0f;
        }
        if (lane == 0 && marked) {
            const int slot = atomicAdd(cntp, 1);
            list[slot] = gt;
        }
        __syncthreads();
    }

    atomicAdd(&Pl[lane], pacc);
    atomicAdd(&Cl[lane], cacc);
    __syncthreads();
    if (tid < NE) {
        atomicAdd(&gP[tid], Pl[tid]);
        atomicAdd(&gC[tid], Cl[tid]);
    }
}

// ---------------------------------------------------------------------------
// Fixup + loss: fp64 recompute of near-tie chain candidates (grid-strided,
// 2048 one-wave blocks), rank-based selection, then last-done block computes
// the balance loss. Unchanged from the verified R6/R7 version.
// ---------------------------------------------------------------------------
__global__ __launch_bounds__(64) void fix_k(
        const float* __restrict__ x,
        const float* __restrict__ Wg,
        const float* __restrict__ bias,
        const float* __restrict__ Aout,
        float* __restrict__ gates,
        float* __restrict__ idxf,
        const float* __restrict__ gP,
        float* __restrict__ gC,
        const int* __restrict__ cntp,
        int*   __restrict__ done,
        const int* __restrict__ list,
        float* __restrict__ lossOut) {
    __shared__ __align__(16) float  sS[64];
    __shared__ __align__(16) float  bS[64];
    __shared__ __align__(16) int    bI[64];
    __shared__ __align__(16) double dS[64];
    __shared__ __align__(16) double dR[64];

    const int lane = threadIdx.x;
    const int cnt = *cntp;
    float cacc = 0.0f;

    for (int idx = blockIdx.x; idx < cnt; idx += gridDim.x) {
        const int t = list[idx];
        const float lg  = Aout[(size_t)t * NE + lane];
        const float a32 = 1.0f / (1.0f + expf(-lg));   // same expr as gate_k
        const float bl  = bias[lane];
        const float s32 = a32 + bl;

        // hoist x row: k = 4*lane + 256*m
        const float* xr = x + (size_t)t * DIM;
        float4 xv[8];
#pragma unroll
        for (int m = 0; m < 8; ++m) xv[m] = *(const float4*)(xr + 4 * lane + 256 * m);

        sS[lane] = s32;
        __syncthreads();
        int rank = 0;
#pragma unroll
        for (int j4 = 0; j4 < 16; ++j4) {
            const float4 sv = *(const float4*)&sS[j4 * 4];
            rank += (sv.x > s32 || (sv.x == s32 && (j4 * 4 + 0) < lane));
            rank += (sv.y > s32 || (sv.y == s32 && (j4 * 4 + 1) < lane));
            rank += (sv.z > s32 || (sv.z == s32 && (j4 * 4 + 2) < lane));
            rank += (sv.w > s32 || (sv.w == s32 && (j4 * 4 + 3) < lane));
        }
        bS[rank] = s32;
        bI[rank] = lane;
        __syncthreads();

        // sorted top-16 + chain closure touching ranks 0..8
        float vr[16];
        int   ir[16];
#pragma unroll
        for (int k4 = 0; k4 < 4; ++k4) {
            const float4 vv = *(const float4*)&bS[k4 * 4];
            const int4   ii = *(const int4*)&bI[k4 * 4];
            vr[k4 * 4 + 0] = vv.x; vr[k4 * 4 + 1] = vv.y;
            vr[k4 * 4 + 2] = vv.z; vr[k4 * 4 + 3] = vv.w;
            ir[k4 * 4 + 0] = ii.x; ir[k4 * 4 + 1] = ii.y;
            ir[k4 * 4 + 2] = ii.z; ir[k4 * 4 + 3] = ii.w;
        }
        bool needs[16];
#pragma unroll
        for (int k = 0; k < 16; ++k) needs[k] = false;
#pragma unroll
        for (int k = 1; k <= 8; ++k)
            if (vr[k - 1] - vr[k] < TAU) { needs[k - 1] = true; needs[k] = true; }
#pragma unroll
        for (int k = 9; k < 16; ++k)
            if (needs[k - 1] && (vr[k - 1] - vr[k] < TAU)) needs[k] = true;

        unsigned long long mb = 0ull;
#pragma unroll
        for (int k = 0; k < 16; ++k)
            if (needs[k]) mb |= (1ull << ir[k]);

        // fp64 recompute of candidates, two at a time
        double ad = (double)a32;
        while (mb) {
            const int e0 = __ffsll(mb) - 1;
            mb &= mb - 1;
            int e1 = -1;
            if (mb) { e1 = __ffsll(mb) - 1; mb &= mb - 1; }
            const float* wr0 = Wg + (size_t)e0 * DIM;
            const float* wr1 = Wg + (size_t)((e1 >= 0) ? e1 : e0) * DIM;
            float4 w0[8], w1[8];
#pragma unroll
            for (int m = 0; m < 8; ++m) {
                w0[m] = *(const float4*)(wr0 + 4 * lane + 256 * m);
                w1[m] = *(const float4*)(wr1 + 4 * lane + 256 * m);
            }
            double z0 = 0.0, z1 = 0.0;
#pragma unroll
            for (int m = 0; m < 8; ++m) {
                z0 = fma((double)xv[m].x, (double)w0[m].x, z0);
                z0 = fma((double)xv[m].y, (double)w0[m].y, z0);
                z0 = fma((double)xv[m].z, (double)w0[m].z, z0);
                z0 = fma((double)xv[m].w, (double)w0[m].w, z0);
                z1 = fma((double)xv[m].x, (double)w1[m].x, z1);
                z1 = fma((double)xv[m].y, (double)w1[m].y, z1);
                z1 = fma((double)xv[m].z, (double)w1[m].z, z1);
                z1 = fma((double)xv[m].w, (double)w1[m].w, z1);
            }
#pragma unroll
            for (int off = 32; off; off >>= 1) {
                z0 += __shfl_xor(z0, off, 64);
                z1 += __shfl_xor(z1, off, 64);
            }
            const double af0 = 1.0 / (1.0 + exp(-z0));
            if (lane == e0) ad = af0;
            if (e1 >= 0) {
                const double af1 = 1.0 / (1.0 + exp(-z1));
                if (lane == e1) ad = af1;
            }
        }

        // final fp64 rank-based top-8
        const double sd = ad + (double)bl;
        dS[lane] = sd;
        __syncthreads();
        int r2 = 0;
#pragma unroll
        for (int j2 = 0; j2 < 32; ++j2) {
            const double2 dv = *(const double2*)&dS[j2 * 2];
            r2 += (dv.x > sd || (dv.x == sd && (2 * j2 + 0) < lane));
            r2 += (dv.y > sd || (dv.y == sd && (2 * j2 + 1) < lane));
        }
        dR[r2] = ad;
        __syncthreads();
        const double2 g0 = *(const double2*)&dR[0];
        const double2 g1 = *(const double2*)&dR[2];
        const double2 g2 = *(const double2*)&dR[4];
        const double2 g3 = *(const double2*)&dR[6];
        const double gsum = ((((((g0.x + g0.y) + g1.x) + g1.y) + g2.x) + g2.y) + g3.x) + g3.y;
        const double inv = 1.0 / (gsum + (double)EPSV);

        if (r2 < NACT) {
            gates[(size_t)t * NACT + r2] = (float)(ad * inv);
            idxf [(size_t)t * NACT + r2] = (float)lane;
            cacc += 1.0f;
        }
        __syncthreads();
    }

    atomicAdd(&gC[lane], cacc);
    __threadfence();
    int tk = 0;
    if (lane == 0) tk = atomicAdd(done, 1);
    tk = __shfl(tk, 0, 64);
    if (tk == (int)gridDim.x - 1) {
        __threadfence();
        const float f = gC[lane] * ((float)NE / (float)(NACT * T_TOK));
        const float P = gP[lane] / (float)T_TOK;
        float v = f * P;
#pragma unroll
        for (int off = 32; off; off >>= 1) v += __shfl_xor(v, off, 64);
        if (lane == 0) lossOut[0] = ALPHA * v;
    }
}

extern "C" void kernel_launch(void* const* d_in, const int* in_sizes, int n_in,
                              void* d_out, int out_size, void* d_ws, size_t ws_size,
                              hipStream_t stream) {
    const float* x    = (const float*)d_in[0];
    const float* Wg   = (const float*)d_in[1];
    const float* bias = (const float*)d_in[2];
    float* out = (float*)d_out;
    float* gates = out;
    float* idxf  = out + (size_t)T_TOK * NACT;
    float* loss  = out + 2 * (size_t)T_TOK * NACT;

    // workspace layout (16B-aligned sections):
    //   [0, 16MB)    Apart: 4 k-quarter partial logit slices
    //   [16MB, 20MB) Aout: summed logits (fix_k input)
    //   [20MB, ...)  gP[64], gC[64], cntp, done, list[16384]
    float* Apart = (float*)d_ws;
    float* Aout  = (float*)((char*)d_ws + (16u << 20));
    float* gP    = (float*)((char*)d_ws + (20u << 20));
    float* gC    = gP + NE;
    int*   cntp  = (int*)(gC + NE);
    int*   done  = cntp + 1;
    int*   list  = done + 1;

    gemm_k<<<256, 1024, 0, stream>>>(x, Wg, Apart, gP);
    gate_k<<<T_TOK / 16, 256, 0, stream>>>(Apart, bias, Aout, gates, idxf,
                                           gP, gC, cntp, list);
    fix_k<<<2048, 64, 0, stream>>>(x, Wg, bias, Aout, gates, idxf,
                                   gP, gC, cntp, done, list, loss);
}

// Round 17
// 291.127 us; speedup vs baseline: 1.1155x; 1.1155x over previous
//
#include <hip/hip_runtime.h>
#include <math.h>

#define T_TOK 16384
#define DIM   2048
#define NE    64
#define NACT  8
#define ALPHA 1e-4f
#define EPSV  1e-9f
#define TAU   2.5e-4f

#define WPITCH 520   // shorts per W row in LDS (R7-verified layout)
#define GATE_BLOCKS (T_TOK / 16)   // 1024

typedef __attribute__((ext_vector_type(8))) short bf16x8;
typedef __attribute__((ext_vector_type(4))) float f32x4;

// RNE float->bf16 (values finite/small; no nan handling needed)
__device__ inline unsigned short bf16_rne(float f) {
    unsigned b = __float_as_uint(f);
    unsigned r = b + 0x7FFFu + ((b >> 16) & 1u);
    return (unsigned short)(r >> 16);
}

// ---------------------------------------------------------------------------
// GEMM (R7's HW-verified structure, epilogue de-atomicized):
// W k-slice (64e x 512k, bf16 hi+lo) staged+converted into LDS once per
// block (130 KB); barrier-free K-loop: x via 2 direct 64B-segment gathers
// per group (R7 k-permutation), W via ds_read_b128. 131k scattered x-loads.
// Grid 256 = 64 token-groups x 4 k-quarters; block 1024 thr (16 waves).
// Epilogue: plain stores of partials to Apart[kq]. Block 0 zeroes cntp.
// MFMA 16x16x32 bf16, layouts m89/m120-verified.
// ---------------------------------------------------------------------------
__global__ __launch_bounds__(1024) void gemm_k(
        const float* __restrict__ x,
        const float* __restrict__ W,
        float* __restrict__ Apart,
        int*   __restrict__ cntp) {
    __shared__ __align__(16) unsigned short Whs[NE * WPITCH];
    __shared__ __align__(16) unsigned short Wls[NE * WPITCH];

    const int tid = threadIdx.x;
    const int kq  = blockIdx.x & 3;
    const int tg  = blockIdx.x >> 2;
    const int tokBase = tg * 256;
    const int kb  = kq * 512;

    if (blockIdx.x == 0 && tid == 0) *cntp = 0;

    // ---- stage + convert W slice: thread (e=tid>>4, c=tid&15) does 32 k ----
    // permuted store: group-local float4 m -> shorts at (m&3)*8 + (m>>2)*4
    {
        const int e = tid >> 4;
        const int c = tid & 15;
        const float* wr = W + (size_t)e * DIM + kb + c * 32;
        unsigned short* dh = &Whs[e * WPITCH + c * 32];
        unsigned short* dl = &Wls[e * WPITCH + c * 32];
#pragma unroll
        for (int m = 0; m < 8; ++m) {
            const float4 v = *(const float4*)(wr + m * 4);
            const float f[4] = {v.x, v.y, v.z, v.w};
            unsigned short hp[4], lp[4];
#pragma unroll
            for (int u = 0; u < 4; ++u) {
                const unsigned bb = __float_as_uint(f[u]);
                const unsigned hb = bb & 0xFFFF0000u;
                hp[u] = (unsigned short)(hb >> 16);
                lp[u] = bf16_rne(f[u] - __uint_as_float(hb));
            }
            const int dpos = (m & 3) * 8 + (m >> 2) * 4;
            *(ushort4*)(dh + dpos) = *(const ushort4*)hp;
            *(ushort4*)(dl + dpos) = *(const ushort4*)lp;
        }
    }
    __syncthreads();

    const int wv   = tid >> 6;
    const int lane = tid & 63;
    const int c15  = lane & 15;
    const int q    = lane >> 4;

    // lane's k-base within a 32-group is q*4 (permuted layout)
    const float* xp = x + (size_t)(tokBase + wv * 16 + c15) * DIM + kb + q * 4;
    const unsigned short* whB = &Whs[c15 * WPITCH + q * 8];
    const unsigned short* wlB = &Wls[c15 * WPITCH + q * 8];

    f32x4 acc[4];
#pragma unroll
    for (int j = 0; j < 4; ++j) acc[j] = (f32x4){0.f, 0.f, 0.f, 0.f};

    float4 ra[2][2];
    bf16x8 rh[2][4], rl[2][4];

#define LOADSTEP(s, st) {                                                 \
        const float* xpc = xp + 32 * (st);                                \
        ra[s][0] = *(const float4*)xpc;                                   \
        ra[s][1] = *(const float4*)(xpc + 16);                            \
        _Pragma("unroll")                                                 \
        for (int j = 0; j < 4; ++j) {                                     \
            rh[s][j] = *(const bf16x8*)(whB + j * 16 * WPITCH + (st) * 32); \
            rl[s][j] = *(const bf16x8*)(wlB + j * 16 * WPITCH + (st) * 32); \
        }                                                                 \
    }

#define COMPSTEP(s) {                                                     \
        bf16x8 ah, al;                                                    \
        {                                                                 \
            float f[8] = {ra[s][0].x, ra[s][0].y, ra[s][0].z, ra[s][0].w, \
                          ra[s][1].x, ra[s][1].y, ra[s][1].z, ra[s][1].w};\
            _Pragma("unroll")                                             \
            for (int i = 0; i < 8; ++i) {                                 \
                const unsigned bb = __float_as_uint(f[i]);                \
                const unsigned hb = bb & 0xFFFF0000u;                     \
                ah[i] = (short)(hb >> 16);                                \
                al[i] = (short)bf16_rne(f[i] - __uint_as_float(hb));      \
            }                                                             \
        }                                                                 \
        _Pragma("unroll")                                                 \
        for (int j = 0; j < 4; ++j) {                                     \
            acc[j] = __builtin_amdgcn_mfma_f32_16x16x32_bf16(ah, rh[s][j], acc[j], 0, 0, 0); \
            acc[j] = __builtin_amdgcn_mfma_f32_16x16x32_bf16(ah, rl[s][j], acc[j], 0, 0, 0); \
            acc[j] = __builtin_amdgcn_mfma_f32_16x16x32_bf16(al, rh[s][j], acc[j], 0, 0, 0); \
        }                                                                 \
    }

    LOADSTEP(0, 0);
    LOADSTEP(1, 1);
#pragma unroll
    for (int c = 0; c < 16; c += 2) {
        COMPSTEP(0);
        if (c + 2 < 16) LOADSTEP(0, c + 2);
        COMPSTEP(1);
        if (c + 3 < 16) LOADSTEP(1, c + 3);
    }
#undef LOADSTEP
#undef COMPSTEP

    // ---- epilogue: plain partial stores (C: row=q*4+r token, col=16j+c15)
    float* ap = Apart + (size_t)kq * T_TOK * NE;
    const int trow = tokBase + wv * 16 + q * 4;
#pragma unroll
    for (int j = 0; j < 4; ++j)
#pragma unroll
        for (int r = 0; r < 4; ++r)
            ap[(size_t)(trow + r) * NE + 16 * j + c15] = acc[j][r];
}

// ---------------------------------------------------------------------------
// Gate (R7-verified logic): sum the 4 k-quarter partials (fixed order ->
// deterministic), store summed logits to Aout (bit-exact source for fix_k),
// sigmoid -> rank-based top-8 -> gate normalization, near-tie marking.
// R12: per-block loss partials written with PLAIN STORES to gPp/gCp[b][e]
// (no global atomics -- R13 profile showed the 64-address atomic storm).
// Grid 1024 x 256 (16 tok/block, 4/wave).
// ---------------------------------------------------------------------------
__global__ __launch_bounds__(256) void gate_k(
        const float* __restrict__ Apart,
        const float* __restrict__ bias,
        float* __restrict__ Aout,
        float* __restrict__ gates,
        float* __restrict__ idxf,
        float* __restrict__ gPp,
        float* __restrict__ gCp,
        int*   __restrict__ cntp,
        int*   __restrict__ list) {
    __shared__ __align__(16) float aff[16 * 68];
    __shared__ __align__(16) float sS[4][64];   // scores by lane
    __shared__ __align__(16) float bS[4][64];   // scores by rank
    __shared__ __align__(16) float bA[4][64];   // affinity by rank
    __shared__ float Pl[NE];
    __shared__ float Cl[NE];

    const int tid  = threadIdx.x;
    const int wv   = tid >> 6;
    const int lane = tid & 63;
    const int tokBase = blockIdx.x * 16;

    if (tid < NE) { Pl[tid] = 0.0f; Cl[tid] = 0.0f; }

    {
        const int t  = tid >> 4;
        const int e0 = (tid & 15) * 4;
        const size_t off = (size_t)(tokBase + t) * NE + e0;
        const float4 l0 = *(const float4*)(Apart + 0 * (size_t)T_TOK * NE + off);
        const float4 l1 = *(const float4*)(Apart + 1 * (size_t)T_TOK * NE + off);
        const float4 l2 = *(const float4*)(Apart + 2 * (size_t)T_TOK * NE + off);
        const float4 l3 = *(const float4*)(Apart + 3 * (size_t)T_TOK * NE + off);
        float4 lg;
        lg.x = ((l0.x + l1.x) + l2.x) + l3.x;
        lg.y = ((l0.y + l1.y) + l2.y) + l3.y;
        lg.z = ((l0.z + l1.z) + l2.z) + l3.z;
        lg.w = ((l0.w + l1.w) + l2.w) + l3.w;
        *(float4*)(Aout + off) = lg;            // logits for fix_k (bit-exact)
        float4 af;
        af.x = 1.0f / (1.0f + expf(-lg.x));
        af.y = 1.0f / (1.0f + expf(-lg.y));
        af.z = 1.0f / (1.0f + expf(-lg.z));
        af.w = 1.0f / (1.0f + expf(-lg.w));
        *(float4*)&aff[t * 68 + e0] = af;
    }
    __syncthreads();

    const float b = bias[lane];
    float pacc = 0.0f;
    float cacc = 0.0f;

    for (int it = 0; it < 4; ++it) {
        const int tl = wv * 4 + it;
        const int gt = tokBase + tl;
        const float a = aff[tl * 68 + lane];

        float rs = a;
#pragma unroll
        for (int off = 32; off; off >>= 1) rs += __shfl_xor(rs, off, 64);
        pacc += a / (rs + EPSV);

        const float s = a + b;
        sS[wv][lane] = s;
        __syncthreads();

        int rank = 0;
#pragma unroll
        for (int j4 = 0; j4 < 16; ++j4) {
            const float4 sv = *(const float4*)&sS[wv][j4 * 4];
            rank += (sv.x > s || (sv.x == s && (j4 * 4 + 0) < lane));
            rank += (sv.y > s || (sv.y == s && (j4 * 4 + 1) < lane));
            rank += (sv.z > s || (sv.z == s && (j4 * 4 + 2) < lane));
            rank += (sv.w > s || (sv.w == s && (j4 * 4 + 3) < lane));
        }
        bS[wv][rank] = s;
        bA[wv][rank] = a;
        __syncthreads();

        // marking: min adjacent gap among sorted ranks 0..8
        const float4 p0 = *(const float4*)&bS[wv][0];
        const float4 p1 = *(const float4*)&bS[wv][4];
        const float v8v = bS[wv][8];
        float gmin = p0.x - p0.y;
        gmin = fminf(gmin, p0.y - p0.z);
        gmin = fminf(gmin, p0.z - p0.w);
        gmin = fminf(gmin, p0.w - p1.x);
        gmin = fminf(gmin, p1.x - p1.y);
        gmin = fminf(gmin, p1.y - p1.z);
        gmin = fminf(gmin, p1.z - p1.w);
        gmin = fminf(gmin, p1.w - v8v);
        const bool marked = (gmin < TAU);

        const float4 a0 = *(const float4*)&bA[wv][0];
        const float4 a1 = *(const float4*)&bA[wv][4];
        const float gsum = ((((((a0.x + a0.y) + a0.z) + a0.w) + a1.x) + a1.y) + a1.z) + a1.w;
        const float inv = 1.0f / (gsum + EPSV);

        if (rank < NACT) {
            gates[(size_t)gt * NACT + rank] = a * inv;
            idxf [(size_t)gt * NACT + rank] = (float)lane;
            if (!marked) cacc += 1.0f;
        }
        if (lane == 0 && marked) {
            const int slot = atomicAdd(cntp, 1);
            list[slot] = gt;
        }
        __syncthreads();
    }

    atomicAdd(&Pl[lane], pacc);
    atomicAdd(&Cl[lane], cacc);
    __syncthreads();
    if (tid < NE) {
        gPp[(size_t)blockIdx.x * NE + tid] = Pl[tid];
        gCp[(size_t)blockIdx.x * NE + tid] = Cl[tid];
    }
}

// ---------------------------------------------------------------------------
// Fixup: fp64 recompute of near-tie chain candidates (grid-strided, 2048
// one-wave blocks), rank-based selection. R12: tail REMOVED -- no gC
// atomics, no done counter, no loss (R13 profile: 131k lane-atomics onto
// gC[64]'s 2 cache lines + 2048 serialized done-atomics = the 78us).
// Selections for marked tokens are recovered from idxf by loss_k.
// ---------------------------------------------------------------------------
__global__ __launch_bounds__(64) void fix_k(
        const float* __restrict__ x,
        const float* __restrict__ Wg,
        const float* __restrict__ bias,
        const float* __restrict__ Aout,
        float* __restrict__ gates,
        float* __restrict__ idxf,
        const int* __restrict__ cntp,
        const int* __restrict__ list) {
    __shared__ __align__(16) float  sS[64];
    __shared__ __align__(16) float  bS[64];
    __shared__ __align__(16) int    bI[64];
    __shared__ __align__(16) double dS[64];
    __shared__ __align__(16) double dR[64];

    const int lane = threadIdx.x;
    const int cnt = *cntp;

    for (int idx = blockIdx.x; idx < cnt; idx += gridDim.x) {
        const int t = list[idx];
        const float lg  = Aout[(size_t)t * NE + lane];
        const float a32 = 1.0f / (1.0f + expf(-lg));   // same expr as gate_k
        const float bl  = bias[lane];
        const float s32 = a32 + bl;

        // hoist x row: k = 4*lane + 256*m
        const float* xr = x + (size_t)t * DIM;
        float4 xv[8];
#pragma unroll
        for (int m = 0; m < 8; ++m) xv[m] = *(const float4*)(xr + 4 * lane + 256 * m);

        sS[lane] = s32;
        __syncthreads();
        int rank = 0;
#pragma unroll
        for (int j4 = 0; j4 < 16; ++j4) {
            const float4 sv = *(const float4*)&sS[j4 * 4];
            rank += (sv.x > s32 || (sv.x == s32 && (j4 * 4 + 0) < lane));
            rank += (sv.y > s32 || (sv.y == s32 && (j4 * 4 + 1) < lane));
            rank += (sv.z > s32 || (sv.z == s32 && (j4 * 4 + 2) < lane));
            rank += (sv.w > s32 || (sv.w == s32 && (j4 * 4 + 3) < lane));
        }
        bS[rank] = s32;
        bI[rank] = lane;
        __syncthreads();

        // sorted top-16 + chain closure touching ranks 0..8
        float vr[16];
        int   ir[16];
#pragma unroll
        for (int k4 = 0; k4 < 4; ++k4) {
            const float4 vv = *(const float4*)&bS[k4 * 4];
            const int4   ii = *(const int4*)&bI[k4 * 4];
            vr[k4 * 4 + 0] = vv.x; vr[k4 * 4 + 1] = vv.y;
            vr[k4 * 4 + 2] = vv.z; vr[k4 * 4 + 3] = vv.w;
            ir[k4 * 4 + 0] = ii.x; ir[k4 * 4 + 1] = ii.y;
            ir[k4 * 4 + 2] = ii.z; ir[k4 * 4 + 3] = ii.w;
        }
        bool needs[16];
#pragma unroll
        for (int k = 0; k < 16; ++k) needs[k] = false;
#pragma unroll
        for (int k = 1; k <= 8; ++k)
            if (vr[k - 1] - vr[k] < TAU) { needs[k - 1] = true; needs[k] = true; }
#pragma unroll
        for (int k = 9; k < 16; ++k)
            if (needs[k - 1] && (vr[k - 1] - vr[k] < TAU)) needs[k] = true;

        unsigned long long mb = 0ull;
#pragma unroll
        for (int k = 0; k < 16; ++k)
            if (needs[k]) mb |= (1ull << ir[k]);

        // fp64 recompute of candidates, two at a time
        double ad = (double)a32;
        while (mb) {
            const int e0 = __ffsll(mb) - 1;
            mb &= mb - 1;
            int e1 = -1;
            if (mb) { e1 = __ffsll(mb) - 1; mb &= mb - 1; }
            const float* wr0 = Wg + (size_t)e0 * DIM;
            const float* wr1 = Wg + (size_t)((e1 >= 0) ? e1 : e0) * DIM;
            float4 w0[8], w1[8];
#pragma unroll
            for (int m = 0; m < 8; ++m) {
                w0[m] = *(const float4*)(wr0 + 4 * lane + 256 * m);
                w1[m] = *(const float4*)(wr1 + 4 * lane + 256 * m);
            }
            double z0 = 0.0, z1 = 0.0;
#pragma unroll
            for (int m = 0; m < 8; ++m) {
                z0 = fma((double)xv[m].x, (double)w0[m].x, z0);
                z0 = fma((double)xv[m].y, (double)w0[m].y, z0);
                z0 = fma((double)xv[m].z, (double)w0[m].z, z0);
                z0 = fma((double)xv[m].w, (double)w0[m].w, z0);
                z1 = fma((double)xv[m].x, (double)w1[m].x, z1);
                z1 = fma((double)xv[m].y, (double)w1[m].y, z1);
                z1 = fma((double)xv[m].z, (double)w1[m].z, z1);
                z1 = fma((double)xv[m].w, (double)w1[m].w, z1);
            }
#pragma unroll
            for (int off = 32; off; off >>= 1) {
                z0 += __shfl_xor(z0, off, 64);
                z1 += __shfl_xor(z1, off, 64);
            }
            const double af0 = 1.0 / (1.0 + exp(-z0));
            if (lane == e0) ad = af0;
            if (e1 >= 0) {
                const double af1 = 1.0 / (1.0 + exp(-z1));
                if (lane == e1) ad = af1;
            }
        }

        // final fp64 rank-based top-8
        const double sd = ad + (double)bl;
        dS[lane] = sd;
        __syncthreads();
        int r2 = 0;
#pragma unroll
        for (int j2 = 0; j2 < 32; ++j2) {
            const double2 dv = *(const double2*)&dS[j2 * 2];
            r2 += (dv.x > sd || (dv.x == sd && (2 * j2 + 0) < lane));
            r2 += (dv.y > sd || (dv.y == sd && (2 * j2 + 1) < lane));
        }
        dR[r2] = ad;
        __syncthreads();
        const double2 g0 = *(const double2*)&dR[0];
        const double2 g1 = *(const double2*)&dR[2];
        const double2 g2 = *(const double2*)&dR[4];
        const double2 g3 = *(const double2*)&dR[6];
        const double gsum = ((((((g0.x + g0.y) + g1.x) + g1.y) + g2.x) + g2.y) + g3.x) + g3.y;
        const double inv = 1.0 / (gsum + (double)EPSV);

        if (r2 < NACT) {
            gates[(size_t)t * NACT + r2] = (float)(ad * inv);
            idxf [(size_t)t * NACT + r2] = (float)lane;
        }
        __syncthreads();
    }
}

// ---------------------------------------------------------------------------
// Loss (R12): one block. Column-sums gate_k's per-block partials
// (coalesced, L2-hot), histograms marked-token selections from final idxf
// (cnt*8 entries, LDS bins), computes balance loss. Deterministic order.
// ---------------------------------------------------------------------------
__global__ __launch_bounds__(256) void loss_k(
        const float* __restrict__ gPp,
        const float* __restrict__ gCp,
        const int*   __restrict__ cntp,
        const int*   __restrict__ list,
        const float* __restrict__ idxf,
        float* __restrict__ lossOut) {
    __shared__ float Ps[4][64];
    __shared__ float Cs[4][64];
    __shared__ float Ch[64];

    const int tid  = threadIdx.x;
    const int wv   = tid >> 6;
    const int lane = tid & 63;

    if (tid < 64) Ch[tid] = 0.0f;

    // wave wv sums blocks [wv*256, wv*256+256): lane e reads gPp[b][e]
    float p = 0.0f, c = 0.0f;
    const int b0 = wv * (GATE_BLOCKS / 4);
    for (int b = b0; b < b0 + GATE_BLOCKS / 4; ++b) {
        p += gPp[(size_t)b * NE + lane];
        c += gCp[(size_t)b * NE + lane];
    }
    Ps[wv][lane] = p;
    Cs[wv][lane] = c;
    __syncthreads();

    // histogram marked tokens' final selections
    const int cnt = *cntp;
    for (int i = tid; i < cnt * NACT; i += 256) {
        const int t = list[i >> 3];
        const int e = (int)idxf[(size_t)t * NACT + (i & 7)];
        atomicAdd(&Ch[e], 1.0f);
    }
    __syncthreads();

    if (tid < 64) {
        const float P = (((Ps[0][tid] + Ps[1][tid]) + Ps[2][tid]) + Ps[3][tid]) / (float)T_TOK;
        const float C = (((Cs[0][tid] + Cs[1][tid]) + Cs[2][tid]) + Cs[3][tid]) + Ch[tid];
        const float f = C * ((float)NE / (float)(NACT * T_TOK));
        float v = f * P;
#pragma unroll
        for (int off = 32; off; off >>= 1) v += __shfl_xor(v, off, 64);
        if (tid == 0) lossOut[0] = ALPHA * v;
    }
}

extern "C" void kernel_launch(void* const* d_in, const int* in_sizes, int n_in,
                              void* d_out, int out_size, void* d_ws, size_t ws_size,
                              hipStream_t stream) {
    const float* x    = (const float*)d_in[0];
    const float* Wg   = (const float*)d_in[1];
    const float* bias = (const float*)d_in[2];
    float* out = (float*)d_out;
    float* gates = out;
    float* idxf  = out + (size_t)T_TOK * NACT;
    float* loss  = out + 2 * (size_t)T_TOK * NACT;

    // workspace layout (16B-aligned sections):
    //   [0, 16MB)        Apart: 4 k-quarter partial logit slices
    //   [16MB, 20MB)     Aout: summed logits (fix_k input)
    //   [20MB, 20.25MB)  gPp: per-gate-block P partials (1024 x 64)
    //   [20.25MB, 20.5MB) gCp: per-gate-block C partials (1024 x 64)
    //   [20.5MB, ...)    cntp, list[16384]
    float* Apart = (float*)d_ws;
    float* Aout  = (float*)((char*)d_ws + (16u << 20));
    float* gPp   = (float*)((char*)d_ws + (20u << 20));
    float* gCp   = (float*)((char*)d_ws + (20u << 20) + (256u << 10));
    int*   cntp  = (int*)  ((char*)d_ws + (20u << 20) + (512u << 10));
    int*   list  = cntp + 4;

    gemm_k<<<256, 1024, 0, stream>>>(x, Wg, Apart, cntp);
    gate_k<<<GATE_BLOCKS, 256, 0, stream>>>(Apart, bias, Aout, gates, idxf,
                                            gPp, gCp, cntp, list);
    fix_k<<<2048, 64, 0, stream>>>(x, Wg, bias, Aout, gates, idxf, cntp, list);
    loss_k<<<1, 256, 0, stream>>>(gPp, gCp, cntp, list, idxf, loss);
}